// Round 1
// baseline (519.177 us; speedup 1.0000x reference)
//
#include <hip/hip_runtime.h>

typedef unsigned int u32;
typedef unsigned short u16;
typedef __attribute__((ext_vector_type(4))) float f32x4;
typedef __attribute__((ext_vector_type(4))) int i32x4;
typedef __attribute__((ext_vector_type(2))) int i32x2;
typedef __attribute__((ext_vector_type(8))) short s16x8;

#define N_NODES 8192
#define F_DIM 512

// XOR slot swizzle for the [m][k]-contiguous LDS tiles (stride 128B, 8 slots of 16B).
// Reads (m = base + lane&15) are conflict-free; transpose-writes are also balanced.
__device__ __forceinline__ int fm_swz(int m) {
    return ((m >> 2) & 7) ^ ((m & 3) << 1);
}

__device__ __forceinline__ u16 f2bf(float x) {
    u32 u = __builtin_bit_cast(u32, x);
    u = (u + 0x7FFFu + ((u >> 16) & 1u)) >> 16;
    return (u16)u;
}

__device__ __forceinline__ void glds16(const u16* g, u16* l) {
    __builtin_amdgcn_global_load_lds((const __attribute__((address_space(1))) u32*)g,
                                     (__attribute__((address_space(3))) u32*)l, 16, 0, 0);
}

// Shared MFMA inner step: A,B are [128 rows][64 k] bf16 tiles, row stride 64 elems (128B),
// A slots swizzled by fm_swz(row), B slots swizzled by (row&7).
__device__ __forceinline__ void mfma_step(const u16* A, const u16* B, int wm, int wn,
                                          int col, int quad, f32x4 (&acc)[4][4]) {
#pragma unroll
    for (int s2 = 0; s2 < 2; ++s2) {
        s16x8 af[4], bfr[4];
#pragma unroll
        for (int mi = 0; mi < 4; ++mi) {
            int m = wm * 64 + mi * 16 + col;
            int kc = s2 * 4 + quad;
            af[mi] = *(const s16x8*)&A[m * 64 + ((kc ^ fm_swz(m)) << 3)];
        }
#pragma unroll
        for (int ni = 0; ni < 4; ++ni) {
            int rr = wn * 64 + ni * 16 + col;
            int kc = s2 * 4 + quad;
            bfr[ni] = *(const s16x8*)&B[rr * 64 + ((kc ^ (rr & 7)) << 3)];
        }
#pragma unroll
        for (int mi = 0; mi < 4; ++mi)
#pragma unroll
            for (int ni = 0; ni < 4; ++ni)
                acc[mi][ni] = __builtin_amdgcn_mfma_f32_16x16x32_bf16(af[mi], bfr[ni],
                                                                      acc[mi][ni], 0, 0, 0);
    }
}

// ---------------- Kernel 1: Yt[f][i] = bf16( sum_c W[c][f] * X[i][c] ) ----------------
__global__ __launch_bounds__(256, 1)
void k1_xw(const float* __restrict__ X, const float* __restrict__ W, u16* __restrict__ Yt) {
    __shared__ __align__(16) u16 Wl[128 * 64];
    __shared__ __align__(16) u16 Xl[128 * 64];

    const int tid = threadIdx.x;
    const int lane = tid & 63;
    const int wave = tid >> 6;
    const int wm = wave >> 1, wn = wave & 1;
    const int col = lane & 15, quad = lane >> 4;

    const int f0 = (blockIdx.x & 3) * 128;   // M dim (f)
    const int i0 = (blockIdx.x >> 2) * 128;  // N dim (i)

    const int cgrp = tid & 31;  // W: f-group of 4
    const int kk   = tid >> 5;  // W: k-octet
    const int xcq  = tid & 15;  // X: c-quad group
    const int xig  = tid >> 4;  // X: i-group of 8

    f32x4 wr[8], xr[8];
    {
        const float* wp = W + (size_t)(kk * 8) * F_DIM + f0 + cgrp * 4;
        const float* xp = X + (size_t)(i0 + xig * 8) * F_DIM + xcq * 4;
#pragma unroll
        for (int r = 0; r < 8; ++r) wr[r] = *(const f32x4*)(wp + (size_t)r * F_DIM);
#pragma unroll
        for (int r = 0; r < 8; ++r) xr[r] = *(const f32x4*)(xp + (size_t)r * F_DIM);
    }

    f32x4 acc[4][4] = {};

    for (int s = 0; s < 8; ++s) {
        __syncthreads();  // previous compute done reading LDS
        // transpose+convert W tile -> Wl [f][c]
#pragma unroll
        for (int mm = 0; mm < 4; ++mm) {
            int m = cgrp * 4 + mm;
            u32 q0 = ((u32)f2bf(wr[1][mm]) << 16) | f2bf(wr[0][mm]);
            u32 q1 = ((u32)f2bf(wr[3][mm]) << 16) | f2bf(wr[2][mm]);
            u32 q2 = ((u32)f2bf(wr[5][mm]) << 16) | f2bf(wr[4][mm]);
            u32 q3 = ((u32)f2bf(wr[7][mm]) << 16) | f2bf(wr[6][mm]);
            i32x4 v = {(int)q0, (int)q1, (int)q2, (int)q3};
            *(i32x4*)&Wl[m * 64 + ((kk ^ fm_swz(m)) << 3)] = v;
        }
        // convert X tile -> Xl [i][c]
#pragma unroll
        for (int r = 0; r < 8; ++r) {
            int row = xig * 8 + r;
            u32 a = ((u32)f2bf(xr[r][1]) << 16) | f2bf(xr[r][0]);
            u32 b = ((u32)f2bf(xr[r][3]) << 16) | f2bf(xr[r][2]);
            int kc = xcq >> 1, half = xcq & 1;
            i32x2 v = {(int)a, (int)b};
            *(i32x2*)&Xl[row * 64 + ((kc ^ (row & 7)) << 3) + half * 4] = v;
        }
        __syncthreads();
        if (s + 1 < 8) {  // prefetch next tile into regs while computing
            int c0 = (s + 1) * 64;
            const float* wp = W + (size_t)(c0 + kk * 8) * F_DIM + f0 + cgrp * 4;
            const float* xp = X + (size_t)(i0 + xig * 8) * F_DIM + c0 + xcq * 4;
#pragma unroll
            for (int r = 0; r < 8; ++r) wr[r] = *(const f32x4*)(wp + (size_t)r * F_DIM);
#pragma unroll
            for (int r = 0; r < 8; ++r) xr[r] = *(const f32x4*)(xp + (size_t)r * F_DIM);
        }
        mfma_step(Wl, Xl, wm, wn, col, quad, acc);
    }

    // epilogue: store Yt[f][i] bf16
#pragma unroll
    for (int mi = 0; mi < 4; ++mi)
#pragma unroll
        for (int r = 0; r < 4; ++r) {
            int f = f0 + wm * 64 + mi * 16 + quad * 4 + r;
#pragma unroll
            for (int ni = 0; ni < 4; ++ni) {
                int i = i0 + wn * 64 + ni * 16 + col;
                Yt[(size_t)f * N_NODES + i] = f2bf(acc[mi][ni][r]);
            }
        }
}

// -------- Kernel 2: out[j][f] = relu( rsqrt(max(deg_j,1)) * sum_i adj[i][j]*Y[i][f] ) --------
__global__ __launch_bounds__(256, 1)
void k2_agg(const int* __restrict__ adj, const u16* __restrict__ Yt, float* __restrict__ out) {
    __shared__ __align__(16) u16 Ab[2][128 * 64];
    __shared__ __align__(16) u16 Bb[2][128 * 64];
    __shared__ int degs[128];

    const int tid = threadIdx.x;
    const int lane = tid & 63;
    const int wave = tid >> 6;
    const int wm = wave >> 1, wn = wave & 1;
    const int col = lane & 15, quad = lane >> 4;

    // swizzle: 4 f-tiles of the same j-stripe share blockIdx%8 -> same XCD L2
    const int j0 = (blockIdx.x & 63) * 128;
    const int f0 = (blockIdx.x >> 6) * 128;

    const int cgrp = tid & 31;  // j-group of 4
    const int kk = tid >> 5;    // k-octet (8 i-rows)

    if (tid < 128) degs[tid] = 0;

    u32 dacc[4] = {0, 0, 0, 0};
    i32x4 av[8];

    const int rowl = lane >> 3;
    const int kcB = (lane & 7) ^ rowl;  // XOR-swizzled chunk this lane fetches

    auto loadA = [&](int i0k) {
        const int* ap = adj + (size_t)(i0k + kk * 8) * N_NODES + j0 + cgrp * 4;
#pragma unroll
        for (int r = 0; r < 8; ++r) av[r] = *(const i32x4*)(ap + (size_t)r * N_NODES);
    };
    auto stageB = [&](int i0k, int buf) {
#pragma unroll
        for (int gg = 0; gg < 4; ++gg) {
            int g = wave * 4 + gg;
            const u16* src = Yt + (size_t)(f0 + g * 8 + rowl) * N_NODES + i0k + kcB * 8;
            glds16(src, &Bb[buf][g * 512]);
        }
    };
    auto writeA = [&](int buf) {
#pragma unroll
        for (int mm = 0; mm < 4; ++mm) {
            int m = cgrp * 4 + mm;
            u32 p0 = (u32)av[0][mm] | ((u32)av[1][mm] << 16);
            u32 p1 = (u32)av[2][mm] | ((u32)av[3][mm] << 16);
            u32 p2 = (u32)av[4][mm] | ((u32)av[5][mm] << 16);
            u32 p3 = (u32)av[6][mm] | ((u32)av[7][mm] << 16);
            dacc[mm] += p0 + p1 + p2 + p3;  // halves bounded by 512 — no carry
            i32x4 v = {(int)(p0 * 0x3F80u), (int)(p1 * 0x3F80u),
                       (int)(p2 * 0x3F80u), (int)(p3 * 0x3F80u)};
            *(i32x4*)&Ab[buf][m * 64 + ((kk ^ fm_swz(m)) << 3)] = v;
        }
    };

    f32x4 acc[4][4] = {};

    // prologue: stage tile 0
    loadA(0);
    stageB(0, 0);
    writeA(0);

    for (int s = 0; s < 128; ++s) {
        const int cur = s & 1;
        __syncthreads();  // buf[cur] fully staged; prior reads of buf[cur^1] done
        if (s + 1 < 128) {
            loadA((s + 1) * 64);          // async int4 loads (VGPR)
            stageB((s + 1) * 64, cur ^ 1);  // async global->LDS
        }
        mfma_step(Ab[cur], Bb[cur], wm, wn, col, quad, acc);
        if (s + 1 < 128) writeA(cur ^ 1);  // convert+transpose into next buffer
    }

    // degree reduction
    __syncthreads();
#pragma unroll
    for (int mm = 0; mm < 4; ++mm) {
        int d = (int)((dacc[mm] & 0xFFFFu) + (dacc[mm] >> 16));
        atomicAdd(&degs[cgrp * 4 + mm], d);
    }
    __syncthreads();

    // fused norm + relu epilogue
#pragma unroll
    for (int mi = 0; mi < 4; ++mi)
#pragma unroll
        for (int r = 0; r < 4; ++r) {
            int jl = wm * 64 + mi * 16 + quad * 4 + r;
            float nv = rsqrtf(fmaxf((float)degs[jl], 1.0f));
            size_t ob = (size_t)(j0 + jl) * F_DIM + f0 + wn * 64;
#pragma unroll
            for (int ni = 0; ni < 4; ++ni) {
                float v = acc[mi][ni][r] * nv;
                out[ob + ni * 16 + col] = fmaxf(v, 0.0f);
            }
        }
}

extern "C" void kernel_launch(void* const* d_in, const int* in_sizes, int n_in,
                              void* d_out, int out_size, void* d_ws, size_t ws_size,
                              hipStream_t stream) {
    (void)in_sizes; (void)n_in; (void)out_size; (void)ws_size;
    const float* X = (const float*)d_in[0];
    const int* adj = (const int*)d_in[1];
    const float* W = (const float*)d_in[2];
    float* out = (float*)d_out;
    u16* Yt = (u16*)d_ws;  // 512*8192 bf16 = 8 MiB

    k1_xw<<<dim3(256), dim3(256), 0, stream>>>(X, W, Yt);
    k2_agg<<<dim3(256), dim3(256), 0, stream>>>(adj, Yt, out);
}